// Round 3
// baseline (772.138 us; speedup 1.0000x reference)
//
#include <hip/hip_runtime.h>
#include <cstdint>
#include <cstddef>

typedef unsigned long long u64;

#define CIN   512
#define H     38
#define W     50
#define HW    1900
#define PH    40
#define PW    52
#define NA    17100
#define NSORT 32768
#define PRE   6000
#define POST  300
#define NW    94        // ceil(6000/64)
#define MTS   6016      // MT row stride (padded)

// ANCHOR_BASE, fp32-exact decimal literals
__constant__ float c_AB[36] = {
  -37.254833f,  -82.50967f,   53.254833f,  98.50967f,
  -82.50967f,  -173.01933f,   98.50967f,  189.01933f,
 -173.01933f,  -354.03867f,  189.01933f,  370.03867f,
  -56.f, -56.f, 72.f, 72.f,
 -120.f,-120.f,136.f,136.f,
 -248.f,-248.f,264.f,264.f,
  -82.50967f,  -37.254833f,   98.50967f,  53.254833f,
 -173.01933f,  -82.50967f,   189.01933f,  98.50967f,
 -354.03867f, -173.01933f,   370.03867f, 189.01933f
};

// ---------------- input zero-pad: x(512,38,50) -> xp(512,40,52) ----------------
__global__ __launch_bounds__(256) void pad_kernel(const float* __restrict__ x, float* __restrict__ xp) {
  int idx = blockIdx.x * 256 + threadIdx.x;          // exactly 512*40*52
  int c   = idx / (PH * PW);
  int rem = idx - c * (PH * PW);
  int yy  = rem / PW;
  int xx  = rem - yy * PW;
  float v = 0.f;
  if (yy >= 1 && yy <= H && xx >= 1 && xx <= W)
    v = x[(size_t)c * HW + (yy - 1) * W + (xx - 1)];
  xp[idx] = v;
}

// ------------- weight transpose: w1(o,i,ky,kx) -> wt[k= r*512+i][o] -------------
__global__ __launch_bounds__(256) void wtrans_kernel(const float* __restrict__ w1, float* __restrict__ wt) {
  __shared__ float tile[9][16][17];
  int o0 = blockIdx.x * 16, i0 = blockIdx.y * 16;
  int tx = threadIdx.x & 15, ty = threadIdx.x >> 4;
  #pragma unroll
  for (int r = 0; r < 9; ++r)
    tile[r][tx][ty] = w1[((size_t)(o0 + ty) * CIN + (i0 + tx)) * 9 + r];
  __syncthreads();
  #pragma unroll
  for (int r = 0; r < 9; ++r)
    wt[((size_t)r * CIN + i0 + ty) * CIN + o0 + tx] = tile[r][ty][tx];
}

// ---- head weights: loc_w(36,512), score_w(18,512) -> wt2[k][o(64 padded)] ----
__global__ __launch_bounds__(256) void wt2prep_kernel(const float* __restrict__ lw, const float* __restrict__ sw,
                                                      float* __restrict__ wt2) {
  int t = blockIdx.x * 256 + threadIdx.x;            // < 512*64
  int k = t >> 6, o = t & 63;
  float v = 0.f;
  if (o < 36)      v = lw[o * CIN + k];
  else if (o < 54) v = sw[(o - 36) * CIN + k];
  wt2[t] = v;
}

// --------- conv1: outer-product streaming, fp32, deterministic ky-split ----------
// Round-2 post-mortem: (size_t)i*stride per load = 64-bit mul + add pair per
// load x 5 loads/kk -> ~26 extra VALU/kk (VALUBusy 46% of 316us = 146us busy vs
// 57us FMA floor). Fix: outer-product form.
//   wave = 64 consecutive p (1 lane each); o-chunk = 16; acc[16]/lane.
//   Per kk: B = 1 coalesced dword/lane (lane-private p, K-invariant offset);
//           A = 4x float4, WAVE-UNIFORM address (scalarizable to s_load);
//           16 v_fmac (A value broadcast via sgpr/vgpr splat x lane's b).
//   All K-loop pointers are induction variables (an += CIN [uniform->SALU],
//   bn += PH*PW) -- zero 64-bit muls in the loop.
//   Depth-4 pipeline, fully static register indices.
// Accumulation order per output element IDENTICAL to proven kernels:
// ky = split (z), kx-major, i ascending within 512-chunk, one fma per k
// -> bit-exact (absmax 0.0 preserved). part layout unchanged.
__global__ __launch_bounds__(64) void conv_gemm_kernel(const float* __restrict__ wt, const float* __restrict__ xp,
                                                       float* __restrict__ part) {
  const int lane  = threadIdx.x;
  const int obase = blockIdx.x * 16;
  const int pbase = blockIdx.y * 64;
  const int ky    = blockIdx.z;            // split index == filter row
  const int p     = pbase + lane;
  const bool pv   = (p < HW);
  const int pc    = pv ? p : (HW - 1);     // clamp: loads stay in-bounds, store guarded
  const int y0    = pc / 50;
  const int x0    = pc - y0 * 50;
  const int boff  = y0 * PW + x0;          // K-invariant per-lane B offset

  float acc[16] = {};

  #pragma unroll 1
  for (int kx = 0; kx < 3; ++kx) {
    const float* __restrict__ ar = wt + ((size_t)(ky * 1536 + kx * 512) * CIN + obase);
    const float* __restrict__ br = xp + (ky * PW + kx + boff);

    float4 a[4][4];
    float  b[4];
    // prologue: stage i = 0..3
    {
      const float* an = ar;
      const float* bn = br;
      #pragma unroll
      for (int u = 0; u < 4; ++u) {
        a[u][0] = *(const float4*)(an + 0);
        a[u][1] = *(const float4*)(an + 4);
        a[u][2] = *(const float4*)(an + 8);
        a[u][3] = *(const float4*)(an + 12);
        b[u]    = *bn;
        an += CIN;
        bn += PH * PW;
      }
    }
    // steady state: compute group i..i+3, refill i+4..i+7 right after each use
    const float* an = ar + 4 * CIN;          // uniform -> SALU induction
    const float* bn = br + 4 * (PH * PW);    // per-lane -> single VALU pair per bump
    #pragma unroll 1
    for (int i = 0; i < 512 - 4; i += 4) {
      #pragma unroll
      for (int u = 0; u < 4; ++u) {
        const float bb = b[u];
        #pragma unroll
        for (int q = 0; q < 4; ++q) {
          acc[q * 4 + 0] += a[u][q].x * bb;
          acc[q * 4 + 1] += a[u][q].y * bb;
          acc[q * 4 + 2] += a[u][q].z * bb;
          acc[q * 4 + 3] += a[u][q].w * bb;
        }
        a[u][0] = *(const float4*)(an + 0);
        a[u][1] = *(const float4*)(an + 4);
        a[u][2] = *(const float4*)(an + 8);
        a[u][3] = *(const float4*)(an + 12);
        b[u]    = *bn;
        an += CIN;
        bn += PH * PW;
      }
    }
    // epilogue: last 4 k's (i = 508..511)
    #pragma unroll
    for (int u = 0; u < 4; ++u) {
      const float bb = b[u];
      #pragma unroll
      for (int q = 0; q < 4; ++q) {
        acc[q * 4 + 0] += a[u][q].x * bb;
        acc[q * 4 + 1] += a[u][q].y * bb;
        acc[q * 4 + 2] += a[u][q].z * bb;
        acc[q * 4 + 3] += a[u][q].w * bb;
      }
    }
  }

  if (pv) {
    float* dst = part + ((size_t)ky * CIN + obase) * HW + p;
    #pragma unroll
    for (int j = 0; j < 16; ++j)
      dst[(size_t)j * HW] = acc[j];
  }
}

// ------------------- h1 = relu(part0+part1+part2 + bias) ----------------------
__global__ __launch_bounds__(256) void reduce_relu_kernel(const float* __restrict__ part, const float* __restrict__ b1,
                                                          float* __restrict__ h1) {
  int idx = blockIdx.x * 256 + threadIdx.x;          // exactly 512*1900
  int o = idx / HW;
  float v = part[idx] + part[(size_t)CIN * HW + idx] + part[(size_t)2 * CIN * HW + idx] + b1[o];
  h1[idx] = v > 0.f ? v : 0.f;
}

// -------------- heads: c2[64][1900] = wt2^T(64x512) * h1(512x1900) ------------
__global__ __launch_bounds__(256) void heads_gemm_kernel(const float* __restrict__ wt2, const float* __restrict__ h1,
                                                         const float* __restrict__ lb, const float* __restrict__ sb,
                                                         float* __restrict__ c2) {
  __shared__ __align__(16) float As[16][64];
  __shared__ __align__(16) float Bs[16][64];
  const int tid   = threadIdx.x;
  const int pbase = blockIdx.x * 64;
  const int krow = tid >> 4;
  const int c4   = (tid & 15) * 4;
  const int to   = (tid & 15) * 4;
  const int tp   = (tid >> 4) * 4;
  float acc[4][4] = {};
  float av[4], bv[4];

  auto loadAB = [&](int k0) {
    int k = k0 + krow;
    const float4 a4 = *(const float4*)&wt2[k * 64 + c4];
    av[0] = a4.x; av[1] = a4.y; av[2] = a4.z; av[3] = a4.w;
    #pragma unroll
    for (int j = 0; j < 4; ++j) {
      int p = pbase + c4 + j;
      bv[j] = (p < HW) ? h1[(size_t)k * HW + p] : 0.f;
    }
  };

  loadAB(0);
  for (int k0 = 0; k0 < CIN; k0 += 16) {
    __syncthreads();
    *(float4*)&As[krow][c4] = make_float4(av[0], av[1], av[2], av[3]);
    *(float4*)&Bs[krow][c4] = make_float4(bv[0], bv[1], bv[2], bv[3]);
    __syncthreads();
    if (k0 + 16 < CIN) loadAB(k0 + 16);
    #pragma unroll
    for (int kk = 0; kk < 16; ++kk) {
      float4 a4 = *(const float4*)&As[kk][to];
      float4 b4 = *(const float4*)&Bs[kk][tp];
      float ar[4] = {a4.x, a4.y, a4.z, a4.w};
      float br[4] = {b4.x, b4.y, b4.z, b4.w};
      #pragma unroll
      for (int ii = 0; ii < 4; ++ii)
        #pragma unroll
        for (int jj = 0; jj < 4; ++jj)
          acc[ii][jj] += ar[ii] * br[jj];
    }
  }
  #pragma unroll
  for (int ii = 0; ii < 4; ++ii) {
    int o = to + ii;
    float bias = 0.f;
    if (o < 36) bias = lb[o]; else if (o < 54) bias = sb[o - 36];
    int p = pbase + tp;
    float* rowp = c2 + (size_t)o * HW;
    #pragma unroll
    for (int jj = 0; jj < 4; ++jj) if (p + jj < HW) rowp[p + jj] = acc[ii][jj] + bias;
  }
}

// ---------------- decode anchors -> roi, validity, sortable key ----------------
__global__ __launch_bounds__(256) void decode_kernel(const float* __restrict__ c2, float* __restrict__ roi,
                                                     u64* __restrict__ keys) {
  int n = blockIdx.x * 256 + threadIdx.x;
  if (n >= NSORT) return;
  if (n >= NA) { keys[n] = ~0ull; return; }
  unsigned p = (unsigned)n / 9u;
  unsigned a = (unsigned)n - p * 9u;
  unsigned y = p / 50u;
  unsigned x = p - y * 50u;
  float dy = c2[(a * 4 + 0) * HW + p];
  float dx = c2[(a * 4 + 1) * HW + p];
  float dh = c2[(a * 4 + 2) * HW + p];
  float dw = c2[(a * 4 + 3) * HW + p];
  float fg = c2[(37 + a * 2) * HW + p];           // score channel a*2+1, rows offset 36
  float sy = (float)(y * 16u), sx = (float)(x * 16u);
  float ay1 = sy + c_AB[a * 4 + 0], ax1 = sx + c_AB[a * 4 + 1];
  float ay2 = sy + c_AB[a * 4 + 2], ax2 = sx + c_AB[a * 4 + 3];
  float ahh = ay2 - ay1, aww = ax2 - ax1;
  float acy = ay1 + 0.5f * ahh, acx = ax1 + 0.5f * aww;
  float cy = dy * ahh + acy, cx = dx * aww + acx;
  float hh = expf(dh) * ahh, ww = expf(dw) * aww;
  float y1 = cy - 0.5f * hh, x1 = cx - 0.5f * ww;
  float y2 = cy + 0.5f * hh, x2 = cx + 0.5f * ww;
  y1 = fminf(fmaxf(y1, 0.f), 608.f); x1 = fminf(fmaxf(x1, 0.f), 800.f);
  y2 = fminf(fmaxf(y2, 0.f), 608.f); x2 = fminf(fmaxf(x2, 0.f), 800.f);
  *(float4*)&roi[(size_t)n * 4] = make_float4(y1, x1, y2, x2);
  bool valid = ((y2 - y1) >= 16.f) && ((x2 - x1) >= 16.f);
  float sc = valid ? fg : -__builtin_huge_valf();
  unsigned m = __float_as_uint(sc);
  m = (m & 0x80000000u) ? ~m : (m | 0x80000000u);   // monotone map: larger score -> larger m
  unsigned km = ~m;                                  // ascending key = descending score
  keys[n] = ((u64)km << 32) | (unsigned)n;           // tie-break: lower index first
}

// ------------------- LDS bitonic sort of one 8192 chunk (asc) ------------------
__global__ __launch_bounds__(1024) void sort_kernel(u64* __restrict__ keys) {
  __shared__ u64 s[8192];
  const int tid = threadIdx.x;
  u64* base = keys + (size_t)blockIdx.x * 8192;
  for (int i = tid; i < 8192; i += 1024) s[i] = base[i];
  __syncthreads();
  for (int k = 2; k <= 8192; k <<= 1) {
    for (int j = k >> 1; j > 0; j >>= 1) {
      for (int i = tid; i < 8192; i += 1024) {
        int l = i ^ j;
        if (l > i) {
          u64 xa = s[i], xb = s[l];
          bool up = ((i & k) == 0);
          if ((xa > xb) == up) { s[i] = xb; s[l] = xa; }
        }
      }
      __syncthreads();
    }
  }
  for (int i = tid; i < 8192; i += 1024) base[i] = s[i];
}

// ------------------------------ merge-path merges ------------------------------
__device__ inline void merge_path(const u64* __restrict__ A, int nA, const u64* __restrict__ B, int nB,
                                  u64* __restrict__ dst, int d0, int cnt, int outLimit) {
  if (d0 >= outLimit || d0 >= nA + nB) return;
  int lo = d0 > nB ? d0 - nB : 0;
  int hi = d0 < nA ? d0 : nA;
  while (lo < hi) {
    int mid = (lo + hi) >> 1;
    if (A[mid] <= B[d0 - 1 - mid]) lo = mid + 1; else hi = mid;
  }
  int i = lo, j = d0 - lo;
  int end = d0 + cnt;
  if (end > nA + nB) end = nA + nB;
  if (end > outLimit) end = outLimit;
  for (int q = d0; q < end; ++q) {
    u64 v;
    if (i < nA && (j >= nB || A[i] <= B[j])) v = A[i++]; else v = B[j++];
    dst[q] = v;
  }
}
__global__ __launch_bounds__(256) void merge1_kernel(const u64* __restrict__ keys, u64* __restrict__ tmp) {
  int pair = blockIdx.y;
  int gid = blockIdx.x * 256 + threadIdx.x;          // 0..1023 per pair
  const u64* A = keys + (size_t)pair * 16384;
  merge_path(A, 8192, A + 8192, 8192, tmp + (size_t)pair * 16384, gid * 16, 16, 16384);
}
__global__ __launch_bounds__(256) void merge2_kernel(const u64* __restrict__ tmp, u64* __restrict__ topk) {
  int gid = blockIdx.x * 256 + threadIdx.x;          // 0..511
  merge_path(tmp, 16384, tmp + 16384, 16384, topk, gid * 16, 16, 6016);
}

// ---------------- gather top-6000 boxes + areas + validity bitmask --------------
__global__ __launch_bounds__(256) void gather_kernel(const u64* __restrict__ topk, const float* __restrict__ roi,
                                                     float* __restrict__ tb, float* __restrict__ areaArr,
                                                     u64* __restrict__ valw) {
  int j = blockIdx.x * 256 + threadIdx.x;            // 6144 threads
  u64 key = (j < 6016) ? topk[j] : ~0ull;
  bool valid = (j < PRE) && ((unsigned)(key >> 32) < 0xFF800000u);   // score > -inf
  if (j < PRE) {
    unsigned idx = (unsigned)key;
    float4 b = *(const float4*)&roi[(size_t)idx * 4];
    *(float4*)&tb[(size_t)j * 4] = b;
    areaArr[j] = (b.z - b.x) * (b.w - b.y);
  }
  u64 mask = __ballot(valid);
  if ((threadIdx.x & 63) == 0) {
    int wi = j >> 6;
    if (wi < NW) valw[wi] = mask;
  }
}

// --------------- suppression bit-matrix MT[w][i]: bits j in word w -------------
__global__ __launch_bounds__(256) void mask_kernel(const float* __restrict__ tb, const float* __restrict__ areaArr,
                                                   u64* __restrict__ MT) {
  int linear = blockIdx.x * 256 + threadIdx.x;
  if (linear >= NW * PRE) return;
  int w = linear / PRE;
  int i = linear - w * PRE;
  u64 bits = 0;
  int jbase = w * 64;
  if (jbase + 63 > i) {
    float4 bi = *(const float4*)&tb[(size_t)i * 4];
    float ai = areaArr[i];
    int jend = jbase + 64; if (jend > PRE) jend = PRE;
    int jst = jbase > i + 1 ? jbase : i + 1;
    for (int j = jst; j < jend; ++j) {
      float4 bj = *(const float4*)&tb[(size_t)j * 4];
      float ty1 = fmaxf(bi.x, bj.x);
      float tx1 = fmaxf(bi.y, bj.y);
      float ty2 = fminf(bi.z, bj.z);
      float tx2 = fminf(bi.w, bj.w);
      float ih = ty2 - ty1; if (ih < 0.f) ih = 0.f;
      float iw = tx2 - tx1; if (iw < 0.f) iw = 0.f;
      float inter = ih * iw;
      float denom = ai + areaArr[j] - inter;
      if (denom < 1e-9f) denom = 1e-9f;
      if (inter / denom > 0.7f) bits |= (1ull << (j - jbase));
    }
  }
  MT[(size_t)w * MTS + i] = bits;
}

__device__ inline u64 shfl_u64(u64 v, int src) {
  int lo = __shfl((int)(unsigned)(v & 0xffffffffull), src, 64);
  int hi = __shfl((int)(unsigned)(v >> 32), src, 64);
  return ((u64)(unsigned)hi << 32) | (unsigned)lo;
}

// ------------- single-wave greedy NMS scan + write first 300 kept --------------
__global__ __launch_bounds__(64) void nms_scan_kernel(const u64* __restrict__ MT, const u64* __restrict__ valw,
                                                      const float* __restrict__ tb, float* __restrict__ out) {
  __shared__ u64 removed[NW];
  __shared__ int keepids[POST];
  const int lane = threadIdx.x;
  for (int wk = lane; wk < NW; wk += 64) removed[wk] = 0;
  __syncthreads();
  int kept = 0;
  bool done = false;
  for (int g = 0; g < NW && !done; ++g) {
    int row = g * 64 + lane;
    u64 cur = (row < PRE) ? MT[(size_t)g * MTS + row] : 0ull;   // box row's own-word suppression bits
    u64 v = valw[g];
    u64 r = removed[g];
    u64 kb = 0;
    u64 remaining = v & ~r;
    while (remaining) {                                // uniform across lanes
      int c = __builtin_ctzll(remaining);
      if (lane == 0) keepids[kept] = g * 64 + c;
      kb |= (1ull << c);
      ++kept;
      if (kept >= POST) { done = true; break; }
      u64 cw = shfl_u64(cur, c);                       // broadcast lane c's word
      r |= cw;
      u64 above = (c == 63) ? 0ull : (~0ull << (c + 1));
      remaining = v & ~r & above;
    }
    if (!done) {
      __syncthreads();
      for (int wk = g + 1 + lane; wk < NW; wk += 64) {
        u64 acc2 = removed[wk];
        u64 m = kb;
        while (m) {
          int b = __builtin_ctzll(m); m &= m - 1;
          acc2 |= MT[(size_t)wk * MTS + g * 64 + b];
        }
        removed[wk] = acc2;
      }
      __syncthreads();
    }
  }
  __syncthreads();
  int kmax = kept < POST ? kept : POST;
  for (int rr = lane; rr < kmax; rr += 64) {
    float4 b = *(const float4*)&tb[(size_t)keepids[rr] * 4];
    *(float4*)&out[(size_t)rr * 4] = b;
  }
}

extern "C" void kernel_launch(void* const* d_in, const int* in_sizes, int n_in,
                              void* d_out, int out_size, void* d_ws, size_t ws_size,
                              hipStream_t stream) {
  (void)in_sizes; (void)n_in; (void)ws_size;
  const float* x  = (const float*)d_in[0];
  const float* w1 = (const float*)d_in[1];
  const float* b1 = (const float*)d_in[2];
  const float* lw = (const float*)d_in[3];
  const float* lb = (const float*)d_in[4];
  const float* sw = (const float*)d_in[5];
  const float* sb = (const float*)d_in[6];
  float* out = (float*)d_out;

  char* wp = (char*)d_ws;
  auto alloc = [&](size_t b) -> void* { void* p = wp; wp += (b + 255) & ~(size_t)255; return p; };
  float* xp      = (float*)alloc((size_t)CIN * PH * PW * 4);   // 4.26 MB
  float* wt      = (float*)alloc((size_t)4608 * CIN * 4);      // 9.44 MB
  float* part    = (float*)alloc((size_t)3 * CIN * HW * 4);    // 11.7 MB
  float* h1      = (float*)alloc((size_t)CIN * HW * 4);        // 3.89 MB
  float* wt2     = (float*)alloc((size_t)CIN * 64 * 4);
  float* c2      = (float*)alloc((size_t)64 * HW * 4);
  float* roi     = (float*)alloc((size_t)NA * 4 * 4);
  u64*   keys    = (u64*)alloc((size_t)NSORT * 8);
  u64*   tmp     = (u64*)alloc((size_t)NSORT * 8);
  u64*   topk    = (u64*)alloc((size_t)8192 * 8);
  float* tb      = (float*)alloc((size_t)PRE * 4 * 4);
  float* areaArr = (float*)alloc((size_t)PRE * 4);
  u64*   valw    = (u64*)alloc((size_t)NW * 8);
  u64*   MT      = (u64*)alloc((size_t)NW * MTS * 8);          // 4.52 MB

  hipMemsetAsync(d_out, 0, (size_t)out_size * 4, stream);

  pad_kernel<<<(CIN * PH * PW) / 256, 256, 0, stream>>>(x, xp);
  wtrans_kernel<<<dim3(32, 32), 256, 0, stream>>>(w1, wt);
  wt2prep_kernel<<<(CIN * 64) / 256, 256, 0, stream>>>(lw, sw, wt2);
  conv_gemm_kernel<<<dim3(32, 30, 3), 64, 0, stream>>>(wt, xp, part);
  reduce_relu_kernel<<<(CIN * HW) / 256, 256, 0, stream>>>(part, b1, h1);
  heads_gemm_kernel<<<30, 256, 0, stream>>>(wt2, h1, lb, sb, c2);
  decode_kernel<<<NSORT / 256, 256, 0, stream>>>(c2, roi, keys);
  sort_kernel<<<4, 1024, 0, stream>>>(keys);
  merge1_kernel<<<dim3(4, 2), 256, 0, stream>>>(keys, tmp);
  merge2_kernel<<<2, 256, 0, stream>>>(tmp, topk);
  gather_kernel<<<24, 256, 0, stream>>>(topk, roi, tb, areaArr, valw);
  mask_kernel<<<(NW * PRE + 255) / 256, 256, 0, stream>>>(tb, areaArr, MT);
  nms_scan_kernel<<<1, 64, 0, stream>>>(MT, valw, tb, out);
}

// Round 4
// 615.526 us; speedup vs baseline: 1.2544x; 1.2544x over previous
//
#include <hip/hip_runtime.h>
#include <cstdint>
#include <cstddef>

typedef unsigned long long u64;

#define CIN   512
#define H     38
#define W     50
#define HW    1900
#define PH    40
#define PW    52
#define NA    17100
#define NSORT 32768
#define PRE   6000
#define POST  300
#define NW    94        // ceil(6000/64)
#define MTS   6016      // MT row stride (padded)

// ANCHOR_BASE, fp32-exact decimal literals
__constant__ float c_AB[36] = {
  -37.254833f,  -82.50967f,   53.254833f,  98.50967f,
  -82.50967f,  -173.01933f,   98.50967f,  189.01933f,
 -173.01933f,  -354.03867f,  189.01933f,  370.03867f,
  -56.f, -56.f, 72.f, 72.f,
 -120.f,-120.f,136.f,136.f,
 -248.f,-248.f,264.f,264.f,
  -82.50967f,  -37.254833f,   98.50967f,  53.254833f,
 -173.01933f,  -82.50967f,   189.01933f,  98.50967f,
 -354.03867f, -173.01933f,   370.03867f, 189.01933f
};

// ---------------- input zero-pad: x(512,38,50) -> xp(512,40,52) ----------------
__global__ __launch_bounds__(256) void pad_kernel(const float* __restrict__ x, float* __restrict__ xp) {
  int idx = blockIdx.x * 256 + threadIdx.x;          // exactly 512*40*52
  int c   = idx / (PH * PW);
  int rem = idx - c * (PH * PW);
  int yy  = rem / PW;
  int xx  = rem - yy * PW;
  float v = 0.f;
  if (yy >= 1 && yy <= H && xx >= 1 && xx <= W)
    v = x[(size_t)c * HW + (yy - 1) * W + (xx - 1)];
  xp[idx] = v;
}

// ------------- weight transpose: w1(o,i,ky,kx) -> wt[k= r*512+i][o] -------------
__global__ __launch_bounds__(256) void wtrans_kernel(const float* __restrict__ w1, float* __restrict__ wt) {
  __shared__ float tile[9][16][17];
  int o0 = blockIdx.x * 16, i0 = blockIdx.y * 16;
  int tx = threadIdx.x & 15, ty = threadIdx.x >> 4;
  #pragma unroll
  for (int r = 0; r < 9; ++r)
    tile[r][tx][ty] = w1[((size_t)(o0 + ty) * CIN + (i0 + tx)) * 9 + r];
  __syncthreads();
  #pragma unroll
  for (int r = 0; r < 9; ++r)
    wt[((size_t)r * CIN + i0 + ty) * CIN + o0 + tx] = tile[r][ty][tx];
}

// ---- head weights: loc_w(36,512), score_w(18,512) -> wt2[k][o(64 padded)] ----
__global__ __launch_bounds__(256) void wt2prep_kernel(const float* __restrict__ lw, const float* __restrict__ sw,
                                                      float* __restrict__ wt2) {
  int t = blockIdx.x * 256 + threadIdx.x;            // < 512*64
  int k = t >> 6, o = t & 63;
  float v = 0.f;
  if (o < 36)      v = lw[o * CIN + k];
  else if (o < 54) v = sw[(o - 36) * CIN + k];
  wt2[t] = v;
}

// --------- conv1 as implicit GEMM, fp32, deterministic 3-way K-split ----------
// Round-0 structure (256 threads, LDS staging, barriers -- the configuration
// whose counters validated the model: ds_read_b128 instrs x 12cyc / 256 CU =
// 171us = measured). Lever: 8x8 micro-tile on a 128x128 block tile halves the
// LDS instrs/FMA twice over (4 b128 per 128 VALU-cyc vs 2 per 32) ->
// LDS:VALU = 192:128 per CU = 1.5x floor (~85us) x 180/256 CU-util.
// Each thread's 8 o's / 8 p's are TWO QUADS 64 APART (c4, c4+64): with b128's
// 16-lane phasing this is 16 distinct 16B addrs/phase = 2-way = free (r0
// measured 0 conflicts on this pattern); a contiguous octet would be 4-way.
// Accumulation order per output element IDENTICAL to r0/r1 (ky split, kx-major,
// i ascending, one fma per k) -> bit-exact.
__global__ __launch_bounds__(256) void conv_gemm_kernel(const float* __restrict__ wt, const float* __restrict__ xp,
                                                        float* __restrict__ part) {
  __shared__ __align__(16) float As[16][128];
  __shared__ __align__(16) float Bs[16][128];
  const int tid   = threadIdx.x;
  const int obase = blockIdx.x * 128;
  const int pbase = blockIdx.y * 128;
  const int split = blockIdx.z;
  const int kbeg = split * 1536, kend = kbeg + 1536;
  const int krow = tid >> 4;          // staging row 0..15
  const int c4   = (tid & 15) * 4;    // staging col quad (quads c4 and c4+64)
  const int to   = (tid & 15) * 4;    // output o quads: to, to+64
  const int tp   = (tid >> 4) * 4;    // output p quads: tp, tp+64
  float acc[8][8] = {};
  float av[8], bv[8];

  auto loadAB = [&](int k0) {
    int k = k0 + krow;
    const float* ap = &wt[(size_t)k * CIN + obase + c4];
    av[0] = ap[0];  av[1] = ap[1];  av[2] = ap[2];  av[3] = ap[3];
    av[4] = ap[64]; av[5] = ap[65]; av[6] = ap[66]; av[7] = ap[67];
    int r = k >> 9;            // k = r*512 + i
    int i = k & 511;
    int ky = r / 3, kx = r - ky * 3;
    const float* xpi = &xp[(size_t)i * (PH * PW)];
    #pragma unroll
    for (int g = 0; g < 2; ++g) {
      #pragma unroll
      for (int j = 0; j < 4; ++j) {
        int p = pbase + c4 + g * 64 + j;
        float v = 0.f;
        if (p < HW) {
          int y = p / W, xx = p - y * W;
          v = xpi[(y + ky) * PW + xx + kx];
        }
        bv[g * 4 + j] = v;
      }
    }
  };

  loadAB(kbeg);
  for (int k0 = kbeg; k0 < kend; k0 += 16) {
    __syncthreads();
    *(float4*)&As[krow][c4]      = make_float4(av[0], av[1], av[2], av[3]);
    *(float4*)&As[krow][c4 + 64] = make_float4(av[4], av[5], av[6], av[7]);
    *(float4*)&Bs[krow][c4]      = make_float4(bv[0], bv[1], bv[2], bv[3]);
    *(float4*)&Bs[krow][c4 + 64] = make_float4(bv[4], bv[5], bv[6], bv[7]);
    __syncthreads();
    if (k0 + 16 < kend) loadAB(k0 + 16);
    #pragma unroll
    for (int kk = 0; kk < 16; ++kk) {
      float4 a0 = *(const float4*)&As[kk][to];
      float4 a1 = *(const float4*)&As[kk][to + 64];
      float4 b0 = *(const float4*)&Bs[kk][tp];
      float4 b1 = *(const float4*)&Bs[kk][tp + 64];
      float ar[8] = {a0.x, a0.y, a0.z, a0.w, a1.x, a1.y, a1.z, a1.w};
      float br[8] = {b0.x, b0.y, b0.z, b0.w, b1.x, b1.y, b1.z, b1.w};
      #pragma unroll
      for (int ii = 0; ii < 8; ++ii)
        #pragma unroll
        for (int jj = 0; jj < 8; ++jj)
          acc[ii][jj] += ar[ii] * br[jj];
    }
  }

  float* dst = part + (size_t)split * CIN * HW;
  #pragma unroll
  for (int ii = 0; ii < 8; ++ii) {
    int o = obase + to + (ii < 4 ? ii : 60 + ii);    // to + ii  or  to + 64 + (ii-4)
    float* rowp = dst + (size_t)o * HW;
    #pragma unroll
    for (int g = 0; g < 2; ++g) {
      int p = pbase + tp + g * 64;
      if (p + 3 < HW) {
        *(float4*)&rowp[p] = make_float4(acc[ii][g*4+0], acc[ii][g*4+1], acc[ii][g*4+2], acc[ii][g*4+3]);
      } else {
        #pragma unroll
        for (int jj = 0; jj < 4; ++jj) if (p + jj < HW) rowp[p + jj] = acc[ii][g*4+jj];
      }
    }
  }
}

// ------------------- h1 = relu(part0+part1+part2 + bias) ----------------------
__global__ __launch_bounds__(256) void reduce_relu_kernel(const float* __restrict__ part, const float* __restrict__ b1,
                                                          float* __restrict__ h1) {
  int idx = blockIdx.x * 256 + threadIdx.x;          // exactly 512*1900
  int o = idx / HW;
  float v = part[idx] + part[(size_t)CIN * HW + idx] + part[(size_t)2 * CIN * HW + idx] + b1[o];
  h1[idx] = v > 0.f ? v : 0.f;
}

// -------------- heads: c2[64][1900] = wt2^T(64x512) * h1(512x1900) ------------
__global__ __launch_bounds__(256) void heads_gemm_kernel(const float* __restrict__ wt2, const float* __restrict__ h1,
                                                         const float* __restrict__ lb, const float* __restrict__ sb,
                                                         float* __restrict__ c2) {
  __shared__ __align__(16) float As[16][64];
  __shared__ __align__(16) float Bs[16][64];
  const int tid   = threadIdx.x;
  const int pbase = blockIdx.x * 64;
  const int krow = tid >> 4;
  const int c4   = (tid & 15) * 4;
  const int to   = (tid & 15) * 4;
  const int tp   = (tid >> 4) * 4;
  float acc[4][4] = {};
  float av[4], bv[4];

  auto loadAB = [&](int k0) {
    int k = k0 + krow;
    const float4 a4 = *(const float4*)&wt2[k * 64 + c4];
    av[0] = a4.x; av[1] = a4.y; av[2] = a4.z; av[3] = a4.w;
    #pragma unroll
    for (int j = 0; j < 4; ++j) {
      int p = pbase + c4 + j;
      bv[j] = (p < HW) ? h1[(size_t)k * HW + p] : 0.f;
    }
  };

  loadAB(0);
  for (int k0 = 0; k0 < CIN; k0 += 16) {
    __syncthreads();
    *(float4*)&As[krow][c4] = make_float4(av[0], av[1], av[2], av[3]);
    *(float4*)&Bs[krow][c4] = make_float4(bv[0], bv[1], bv[2], bv[3]);
    __syncthreads();
    if (k0 + 16 < CIN) loadAB(k0 + 16);
    #pragma unroll
    for (int kk = 0; kk < 16; ++kk) {
      float4 a4 = *(const float4*)&As[kk][to];
      float4 b4 = *(const float4*)&Bs[kk][tp];
      float ar[4] = {a4.x, a4.y, a4.z, a4.w};
      float br[4] = {b4.x, b4.y, b4.z, b4.w};
      #pragma unroll
      for (int ii = 0; ii < 4; ++ii)
        #pragma unroll
        for (int jj = 0; jj < 4; ++jj)
          acc[ii][jj] += ar[ii] * br[jj];
    }
  }
  #pragma unroll
  for (int ii = 0; ii < 4; ++ii) {
    int o = to + ii;
    float bias = 0.f;
    if (o < 36) bias = lb[o]; else if (o < 54) bias = sb[o - 36];
    int p = pbase + tp;
    float* rowp = c2 + (size_t)o * HW;
    #pragma unroll
    for (int jj = 0; jj < 4; ++jj) if (p + jj < HW) rowp[p + jj] = acc[ii][jj] + bias;
  }
}

// ---------------- decode anchors -> roi, validity, sortable key ----------------
__global__ __launch_bounds__(256) void decode_kernel(const float* __restrict__ c2, float* __restrict__ roi,
                                                     u64* __restrict__ keys) {
  int n = blockIdx.x * 256 + threadIdx.x;
  if (n >= NSORT) return;
  if (n >= NA) { keys[n] = ~0ull; return; }
  unsigned p = (unsigned)n / 9u;
  unsigned a = (unsigned)n - p * 9u;
  unsigned y = p / 50u;
  unsigned x = p - y * 50u;
  float dy = c2[(a * 4 + 0) * HW + p];
  float dx = c2[(a * 4 + 1) * HW + p];
  float dh = c2[(a * 4 + 2) * HW + p];
  float dw = c2[(a * 4 + 3) * HW + p];
  float fg = c2[(37 + a * 2) * HW + p];           // score channel a*2+1, rows offset 36
  float sy = (float)(y * 16u), sx = (float)(x * 16u);
  float ay1 = sy + c_AB[a * 4 + 0], ax1 = sx + c_AB[a * 4 + 1];
  float ay2 = sy + c_AB[a * 4 + 2], ax2 = sx + c_AB[a * 4 + 3];
  float ahh = ay2 - ay1, aww = ax2 - ax1;
  float acy = ay1 + 0.5f * ahh, acx = ax1 + 0.5f * aww;
  float cy = dy * ahh + acy, cx = dx * aww + acx;
  float hh = expf(dh) * ahh, ww = expf(dw) * aww;
  float y1 = cy - 0.5f * hh, x1 = cx - 0.5f * ww;
  float y2 = cy + 0.5f * hh, x2 = cx + 0.5f * ww;
  y1 = fminf(fmaxf(y1, 0.f), 608.f); x1 = fminf(fmaxf(x1, 0.f), 800.f);
  y2 = fminf(fmaxf(y2, 0.f), 608.f); x2 = fminf(fmaxf(x2, 0.f), 800.f);
  *(float4*)&roi[(size_t)n * 4] = make_float4(y1, x1, y2, x2);
  bool valid = ((y2 - y1) >= 16.f) && ((x2 - x1) >= 16.f);
  float sc = valid ? fg : -__builtin_huge_valf();
  unsigned m = __float_as_uint(sc);
  m = (m & 0x80000000u) ? ~m : (m | 0x80000000u);   // monotone map: larger score -> larger m
  unsigned km = ~m;                                  // ascending key = descending score
  keys[n] = ((u64)km << 32) | (unsigned)n;           // tie-break: lower index first
}

// ------------------- LDS bitonic sort of one 8192 chunk (asc) ------------------
__global__ __launch_bounds__(1024) void sort_kernel(u64* __restrict__ keys) {
  __shared__ u64 s[8192];
  const int tid = threadIdx.x;
  u64* base = keys + (size_t)blockIdx.x * 8192;
  for (int i = tid; i < 8192; i += 1024) s[i] = base[i];
  __syncthreads();
  for (int k = 2; k <= 8192; k <<= 1) {
    for (int j = k >> 1; j > 0; j >>= 1) {
      for (int i = tid; i < 8192; i += 1024) {
        int l = i ^ j;
        if (l > i) {
          u64 xa = s[i], xb = s[l];
          bool up = ((i & k) == 0);
          if ((xa > xb) == up) { s[i] = xb; s[l] = xa; }
        }
      }
      __syncthreads();
    }
  }
  for (int i = tid; i < 8192; i += 1024) base[i] = s[i];
}

// ------------------------------ merge-path merges ------------------------------
__device__ inline void merge_path(const u64* __restrict__ A, int nA, const u64* __restrict__ B, int nB,
                                  u64* __restrict__ dst, int d0, int cnt, int outLimit) {
  if (d0 >= outLimit || d0 >= nA + nB) return;
  int lo = d0 > nB ? d0 - nB : 0;
  int hi = d0 < nA ? d0 : nA;
  while (lo < hi) {
    int mid = (lo + hi) >> 1;
    if (A[mid] <= B[d0 - 1 - mid]) lo = mid + 1; else hi = mid;
  }
  int i = lo, j = d0 - lo;
  int end = d0 + cnt;
  if (end > nA + nB) end = nA + nB;
  if (end > outLimit) end = outLimit;
  for (int q = d0; q < end; ++q) {
    u64 v;
    if (i < nA && (j >= nB || A[i] <= B[j])) v = A[i++]; else v = B[j++];
    dst[q] = v;
  }
}
__global__ __launch_bounds__(256) void merge1_kernel(const u64* __restrict__ keys, u64* __restrict__ tmp) {
  int pair = blockIdx.y;
  int gid = blockIdx.x * 256 + threadIdx.x;          // 0..1023 per pair
  const u64* A = keys + (size_t)pair * 16384;
  merge_path(A, 8192, A + 8192, 8192, tmp + (size_t)pair * 16384, gid * 16, 16, 16384);
}
__global__ __launch_bounds__(256) void merge2_kernel(const u64* __restrict__ tmp, u64* __restrict__ topk) {
  int gid = blockIdx.x * 256 + threadIdx.x;          // 0..511
  merge_path(tmp, 16384, tmp + 16384, 16384, topk, gid * 16, 16, 6016);
}

// ---------------- gather top-6000 boxes + areas + validity bitmask --------------
__global__ __launch_bounds__(256) void gather_kernel(const u64* __restrict__ topk, const float* __restrict__ roi,
                                                     float* __restrict__ tb, float* __restrict__ areaArr,
                                                     u64* __restrict__ valw) {
  int j = blockIdx.x * 256 + threadIdx.x;            // 6144 threads
  u64 key = (j < 6016) ? topk[j] : ~0ull;
  bool valid = (j < PRE) && ((unsigned)(key >> 32) < 0xFF800000u);   // score > -inf
  if (j < PRE) {
    unsigned idx = (unsigned)key;
    float4 b = *(const float4*)&roi[(size_t)idx * 4];
    *(float4*)&tb[(size_t)j * 4] = b;
    areaArr[j] = (b.z - b.x) * (b.w - b.y);
  }
  u64 mask = __ballot(valid);
  if ((threadIdx.x & 63) == 0) {
    int wi = j >> 6;
    if (wi < NW) valw[wi] = mask;
  }
}

// --------------- suppression bit-matrix MT[w][i]: bits j in word w -------------
__global__ __launch_bounds__(256) void mask_kernel(const float* __restrict__ tb, const float* __restrict__ areaArr,
                                                   u64* __restrict__ MT) {
  int linear = blockIdx.x * 256 + threadIdx.x;
  if (linear >= NW * PRE) return;
  int w = linear / PRE;
  int i = linear - w * PRE;
  u64 bits = 0;
  int jbase = w * 64;
  if (jbase + 63 > i) {
    float4 bi = *(const float4*)&tb[(size_t)i * 4];
    float ai = areaArr[i];
    int jend = jbase + 64; if (jend > PRE) jend = PRE;
    int jst = jbase > i + 1 ? jbase : i + 1;
    for (int j = jst; j < jend; ++j) {
      float4 bj = *(const float4*)&tb[(size_t)j * 4];
      float ty1 = fmaxf(bi.x, bj.x);
      float tx1 = fmaxf(bi.y, bj.y);
      float ty2 = fminf(bi.z, bj.z);
      float tx2 = fminf(bi.w, bj.w);
      float ih = ty2 - ty1; if (ih < 0.f) ih = 0.f;
      float iw = tx2 - tx1; if (iw < 0.f) iw = 0.f;
      float inter = ih * iw;
      float denom = ai + areaArr[j] - inter;
      if (denom < 1e-9f) denom = 1e-9f;
      if (inter / denom > 0.7f) bits |= (1ull << (j - jbase));
    }
  }
  MT[(size_t)w * MTS + i] = bits;
}

__device__ inline u64 shfl_u64(u64 v, int src) {
  int lo = __shfl((int)(unsigned)(v & 0xffffffffull), src, 64);
  int hi = __shfl((int)(unsigned)(v >> 32), src, 64);
  return ((u64)(unsigned)hi << 32) | (unsigned)lo;
}

// ------------- single-wave greedy NMS scan + write first 300 kept --------------
__global__ __launch_bounds__(64) void nms_scan_kernel(const u64* __restrict__ MT, const u64* __restrict__ valw,
                                                      const float* __restrict__ tb, float* __restrict__ out) {
  __shared__ u64 removed[NW];
  __shared__ int keepids[POST];
  const int lane = threadIdx.x;
  for (int wk = lane; wk < NW; wk += 64) removed[wk] = 0;
  __syncthreads();
  int kept = 0;
  bool done = false;
  for (int g = 0; g < NW && !done; ++g) {
    int row = g * 64 + lane;
    u64 cur = (row < PRE) ? MT[(size_t)g * MTS + row] : 0ull;   // box row's own-word suppression bits
    u64 v = valw[g];
    u64 r = removed[g];
    u64 kb = 0;
    u64 remaining = v & ~r;
    while (remaining) {                                // uniform across lanes
      int c = __builtin_ctzll(remaining);
      if (lane == 0) keepids[kept] = g * 64 + c;
      kb |= (1ull << c);
      ++kept;
      if (kept >= POST) { done = true; break; }
      u64 cw = shfl_u64(cur, c);                       // broadcast lane c's word
      r |= cw;
      u64 above = (c == 63) ? 0ull : (~0ull << (c + 1));
      remaining = v & ~r & above;
    }
    if (!done) {
      __syncthreads();
      for (int wk = g + 1 + lane; wk < NW; wk += 64) {
        u64 acc2 = removed[wk];
        u64 m = kb;
        while (m) {
          int b = __builtin_ctzll(m); m &= m - 1;
          acc2 |= MT[(size_t)wk * MTS + g * 64 + b];
        }
        removed[wk] = acc2;
      }
      __syncthreads();
    }
  }
  __syncthreads();
  int kmax = kept < POST ? kept : POST;
  for (int rr = lane; rr < kmax; rr += 64) {
    float4 b = *(const float4*)&tb[(size_t)keepids[rr] * 4];
    *(float4*)&out[(size_t)rr * 4] = b;
  }
}

extern "C" void kernel_launch(void* const* d_in, const int* in_sizes, int n_in,
                              void* d_out, int out_size, void* d_ws, size_t ws_size,
                              hipStream_t stream) {
  (void)in_sizes; (void)n_in; (void)ws_size;
  const float* x  = (const float*)d_in[0];
  const float* w1 = (const float*)d_in[1];
  const float* b1 = (const float*)d_in[2];
  const float* lw = (const float*)d_in[3];
  const float* lb = (const float*)d_in[4];
  const float* sw = (const float*)d_in[5];
  const float* sb = (const float*)d_in[6];
  float* out = (float*)d_out;

  char* wp = (char*)d_ws;
  auto alloc = [&](size_t b) -> void* { void* p = wp; wp += (b + 255) & ~(size_t)255; return p; };
  float* xp      = (float*)alloc((size_t)CIN * PH * PW * 4);   // 4.26 MB
  float* wt      = (float*)alloc((size_t)4608 * CIN * 4);      // 9.44 MB
  float* part    = (float*)alloc((size_t)3 * CIN * HW * 4);    // 11.7 MB
  float* h1      = (float*)alloc((size_t)CIN * HW * 4);        // 3.89 MB
  float* wt2     = (float*)alloc((size_t)CIN * 64 * 4);
  float* c2      = (float*)alloc((size_t)64 * HW * 4);
  float* roi     = (float*)alloc((size_t)NA * 4 * 4);
  u64*   keys    = (u64*)alloc((size_t)NSORT * 8);
  u64*   tmp     = (u64*)alloc((size_t)NSORT * 8);
  u64*   topk    = (u64*)alloc((size_t)8192 * 8);
  float* tb      = (float*)alloc((size_t)PRE * 4 * 4);
  float* areaArr = (float*)alloc((size_t)PRE * 4);
  u64*   valw    = (u64*)alloc((size_t)NW * 8);
  u64*   MT      = (u64*)alloc((size_t)NW * MTS * 8);          // 4.52 MB

  hipMemsetAsync(d_out, 0, (size_t)out_size * 4, stream);

  pad_kernel<<<(CIN * PH * PW) / 256, 256, 0, stream>>>(x, xp);
  wtrans_kernel<<<dim3(32, 32), 256, 0, stream>>>(w1, wt);
  wt2prep_kernel<<<(CIN * 64) / 256, 256, 0, stream>>>(lw, sw, wt2);
  conv_gemm_kernel<<<dim3(4, 15, 3), 256, 0, stream>>>(wt, xp, part);
  reduce_relu_kernel<<<(CIN * HW) / 256, 256, 0, stream>>>(part, b1, h1);
  heads_gemm_kernel<<<30, 256, 0, stream>>>(wt2, h1, lb, sb, c2);
  decode_kernel<<<NSORT / 256, 256, 0, stream>>>(c2, roi, keys);
  sort_kernel<<<4, 1024, 0, stream>>>(keys);
  merge1_kernel<<<dim3(4, 2), 256, 0, stream>>>(keys, tmp);
  merge2_kernel<<<2, 256, 0, stream>>>(tmp, topk);
  gather_kernel<<<24, 256, 0, stream>>>(topk, roi, tb, areaArr, valw);
  mask_kernel<<<(NW * PRE + 255) / 256, 256, 0, stream>>>(tb, areaArr, MT);
  nms_scan_kernel<<<1, 64, 0, stream>>>(MT, valw, tb, out);
}

// Round 5
// 527.742 us; speedup vs baseline: 1.4631x; 1.1663x over previous
//
#include <hip/hip_runtime.h>
#include <cstdint>
#include <cstddef>

typedef unsigned long long u64;

#define CIN   512
#define H     38
#define W     50
#define HW    1900
#define PH    40
#define PW    52
#define NA    17100
#define NSORT 32768
#define PRE   6000
#define POST  300
#define NW    94        // ceil(6000/64)
#define MTS   6016      // MT row stride (padded)
#define TOPN  6016      // padded top-k (>= PRE, x16 aligned)

// ANCHOR_BASE, fp32-exact decimal literals
__constant__ float c_AB[36] = {
  -37.254833f,  -82.50967f,   53.254833f,  98.50967f,
  -82.50967f,  -173.01933f,   98.50967f,  189.01933f,
 -173.01933f,  -354.03867f,  189.01933f,  370.03867f,
  -56.f, -56.f, 72.f, 72.f,
 -120.f,-120.f,136.f,136.f,
 -248.f,-248.f,264.f,264.f,
  -82.50967f,  -37.254833f,   98.50967f,  53.254833f,
 -173.01933f,  -82.50967f,   189.01933f,  98.50967f,
 -354.03867f, -173.01933f,   370.03867f, 189.01933f
};

// ---------------- input zero-pad: x(512,38,50) -> xp(512,40,52) ----------------
__global__ __launch_bounds__(256) void pad_kernel(const float* __restrict__ x, float* __restrict__ xp) {
  int idx = blockIdx.x * 256 + threadIdx.x;          // exactly 512*40*52
  int c   = idx / (PH * PW);
  int rem = idx - c * (PH * PW);
  int yy  = rem / PW;
  int xx  = rem - yy * PW;
  float v = 0.f;
  if (yy >= 1 && yy <= H && xx >= 1 && xx <= W)
    v = x[(size_t)c * HW + (yy - 1) * W + (xx - 1)];
  xp[idx] = v;
}

// ------------- weight transpose: w1(o,i,ky,kx) -> wt[k= r*512+i][o] -------------
__global__ __launch_bounds__(256) void wtrans_kernel(const float* __restrict__ w1, float* __restrict__ wt) {
  __shared__ float tile[9][16][17];
  int o0 = blockIdx.x * 16, i0 = blockIdx.y * 16;
  int tx = threadIdx.x & 15, ty = threadIdx.x >> 4;
  #pragma unroll
  for (int r = 0; r < 9; ++r)
    tile[r][tx][ty] = w1[((size_t)(o0 + ty) * CIN + (i0 + tx)) * 9 + r];
  __syncthreads();
  #pragma unroll
  for (int r = 0; r < 9; ++r)
    wt[((size_t)r * CIN + i0 + ty) * CIN + o0 + tx] = tile[r][ty][tx];
}

// ---- head weights: loc_w(36,512), score_w(18,512) -> wt2[k][o(64 padded)] ----
__global__ __launch_bounds__(256) void wt2prep_kernel(const float* __restrict__ lw, const float* __restrict__ sw,
                                                      float* __restrict__ wt2) {
  int t = blockIdx.x * 256 + threadIdx.x;            // < 512*64
  int k = t >> 6, o = t & 63;
  float v = 0.f;
  if (o < 36)      v = lw[o * CIN + k];
  else if (o < 54) v = sw[(o - 36) * CIN + k];
  wt2[t] = v;
}

// --------- conv1 as implicit GEMM, fp32, deterministic 3-way K-split ----------
// r0 configuration VERBATIM: 64x64 tile, 4x4 micro, 720 blocks (2.8 waves/SIMD).
// Counter-validated: LDS-pipe-bound (ds_read_b128 instrs x 12cyc / 256 CU =
// 171us = measured 172). Rounds 1-4 proved every restructure (bigger micro,
// no-LDS streaming, scalar A) loses to latency/addressing; this is the
// structural optimum for this fp32 GEMM shape. Bit-exact k-order.
__global__ __launch_bounds__(256) void conv_gemm_kernel(const float* __restrict__ wt, const float* __restrict__ xp,
                                                        float* __restrict__ part) {
  __shared__ __align__(16) float As[16][64];
  __shared__ __align__(16) float Bs[16][64];
  const int tid   = threadIdx.x;
  const int obase = blockIdx.x * 64;
  const int pbase = blockIdx.y * 64;
  const int split = blockIdx.z;
  const int kbeg = split * 1536, kend = kbeg + 1536;
  const int krow = tid >> 4;          // staging row 0..15
  const int c4   = (tid & 15) * 4;    // staging col
  const int to   = (tid & 15) * 4;    // output o quad
  const int tp   = (tid >> 4) * 4;    // output p quad
  float acc[4][4] = {};
  float av[4], bv[4];

  auto loadAB = [&](int k0) {
    int k = k0 + krow;
    const float* ap = &wt[(size_t)k * CIN + obase + c4];
    av[0] = ap[0]; av[1] = ap[1]; av[2] = ap[2]; av[3] = ap[3];
    int r = k >> 9;            // k = r*512 + i
    int i = k & 511;
    int ky = r / 3, kx = r - ky * 3;
    const float* xpi = &xp[(size_t)i * (PH * PW)];
    #pragma unroll
    for (int j = 0; j < 4; ++j) {
      int p = pbase + c4 + j;
      float v = 0.f;
      if (p < HW) {
        int y = p / W, xx = p - y * W;
        v = xpi[(y + ky) * PW + xx + kx];
      }
      bv[j] = v;
    }
  };

  loadAB(kbeg);
  for (int k0 = kbeg; k0 < kend; k0 += 16) {
    __syncthreads();
    *(float4*)&As[krow][c4] = make_float4(av[0], av[1], av[2], av[3]);
    *(float4*)&Bs[krow][c4] = make_float4(bv[0], bv[1], bv[2], bv[3]);
    __syncthreads();
    if (k0 + 16 < kend) loadAB(k0 + 16);
    #pragma unroll
    for (int kk = 0; kk < 16; ++kk) {
      float4 a4 = *(const float4*)&As[kk][to];
      float4 b4 = *(const float4*)&Bs[kk][tp];
      float ar[4] = {a4.x, a4.y, a4.z, a4.w};
      float br[4] = {b4.x, b4.y, b4.z, b4.w};
      #pragma unroll
      for (int ii = 0; ii < 4; ++ii)
        #pragma unroll
        for (int jj = 0; jj < 4; ++jj)
          acc[ii][jj] += ar[ii] * br[jj];
    }
  }
  float* dst = part + (size_t)split * CIN * HW;
  #pragma unroll
  for (int ii = 0; ii < 4; ++ii) {
    int o = obase + to + ii;
    int p = pbase + tp;
    float* rowp = dst + (size_t)o * HW;
    if (p + 3 < HW) {
      *(float4*)&rowp[p] = make_float4(acc[ii][0], acc[ii][1], acc[ii][2], acc[ii][3]);
    } else {
      #pragma unroll
      for (int jj = 0; jj < 4; ++jj) if (p + jj < HW) rowp[p + jj] = acc[ii][jj];
    }
  }
}

// ------------------- h1 = relu(part0+part1+part2 + bias) ----------------------
__global__ __launch_bounds__(256) void reduce_relu_kernel(const float* __restrict__ part, const float* __restrict__ b1,
                                                          float* __restrict__ h1) {
  int idx = blockIdx.x * 256 + threadIdx.x;          // exactly 512*1900
  int o = idx / HW;
  float v = part[idx] + part[(size_t)CIN * HW + idx] + part[(size_t)2 * CIN * HW + idx] + b1[o];
  h1[idx] = v > 0.f ? v : 0.f;
}

// -------------- heads: c2[64][1900] = wt2^T(64x512) * h1(512x1900) ------------
__global__ __launch_bounds__(256) void heads_gemm_kernel(const float* __restrict__ wt2, const float* __restrict__ h1,
                                                         const float* __restrict__ lb, const float* __restrict__ sb,
                                                         float* __restrict__ c2) {
  __shared__ __align__(16) float As[16][64];
  __shared__ __align__(16) float Bs[16][64];
  const int tid   = threadIdx.x;
  const int pbase = blockIdx.x * 64;
  const int krow = tid >> 4;
  const int c4   = (tid & 15) * 4;
  const int to   = (tid & 15) * 4;
  const int tp   = (tid >> 4) * 4;
  float acc[4][4] = {};
  float av[4], bv[4];

  auto loadAB = [&](int k0) {
    int k = k0 + krow;
    const float4 a4 = *(const float4*)&wt2[k * 64 + c4];
    av[0] = a4.x; av[1] = a4.y; av[2] = a4.z; av[3] = a4.w;
    #pragma unroll
    for (int j = 0; j < 4; ++j) {
      int p = pbase + c4 + j;
      bv[j] = (p < HW) ? h1[(size_t)k * HW + p] : 0.f;
    }
  };

  loadAB(0);
  for (int k0 = 0; k0 < CIN; k0 += 16) {
    __syncthreads();
    *(float4*)&As[krow][c4] = make_float4(av[0], av[1], av[2], av[3]);
    *(float4*)&Bs[krow][c4] = make_float4(bv[0], bv[1], bv[2], bv[3]);
    __syncthreads();
    if (k0 + 16 < CIN) loadAB(k0 + 16);
    #pragma unroll
    for (int kk = 0; kk < 16; ++kk) {
      float4 a4 = *(const float4*)&As[kk][to];
      float4 b4 = *(const float4*)&Bs[kk][tp];
      float ar[4] = {a4.x, a4.y, a4.z, a4.w};
      float br[4] = {b4.x, b4.y, b4.z, b4.w};
      #pragma unroll
      for (int ii = 0; ii < 4; ++ii)
        #pragma unroll
        for (int jj = 0; jj < 4; ++jj)
          acc[ii][jj] += ar[ii] * br[jj];
    }
  }
  #pragma unroll
  for (int ii = 0; ii < 4; ++ii) {
    int o = to + ii;
    float bias = 0.f;
    if (o < 36) bias = lb[o]; else if (o < 54) bias = sb[o - 36];
    int p = pbase + tp;
    float* rowp = c2 + (size_t)o * HW;
    #pragma unroll
    for (int jj = 0; jj < 4; ++jj) if (p + jj < HW) rowp[p + jj] = acc[ii][jj] + bias;
  }
}

// ---------------- decode anchors -> roi, validity, sortable key ----------------
__global__ __launch_bounds__(256) void decode_kernel(const float* __restrict__ c2, float* __restrict__ roi,
                                                     u64* __restrict__ keys) {
  int n = blockIdx.x * 256 + threadIdx.x;
  if (n >= NSORT) return;
  if (n >= NA) { keys[n] = ~0ull; return; }
  unsigned p = (unsigned)n / 9u;
  unsigned a = (unsigned)n - p * 9u;
  unsigned y = p / 50u;
  unsigned x = p - y * 50u;
  float dy = c2[(a * 4 + 0) * HW + p];
  float dx = c2[(a * 4 + 1) * HW + p];
  float dh = c2[(a * 4 + 2) * HW + p];
  float dw = c2[(a * 4 + 3) * HW + p];
  float fg = c2[(37 + a * 2) * HW + p];           // score channel a*2+1, rows offset 36
  float sy = (float)(y * 16u), sx = (float)(x * 16u);
  float ay1 = sy + c_AB[a * 4 + 0], ax1 = sx + c_AB[a * 4 + 1];
  float ay2 = sy + c_AB[a * 4 + 2], ax2 = sx + c_AB[a * 4 + 3];
  float ahh = ay2 - ay1, aww = ax2 - ax1;
  float acy = ay1 + 0.5f * ahh, acx = ax1 + 0.5f * aww;
  float cy = dy * ahh + acy, cx = dx * aww + acx;
  float hh = expf(dh) * ahh, ww = expf(dw) * aww;
  float y1 = cy - 0.5f * hh, x1 = cx - 0.5f * ww;
  float y2 = cy + 0.5f * hh, x2 = cx + 0.5f * ww;
  y1 = fminf(fmaxf(y1, 0.f), 608.f); x1 = fminf(fmaxf(x1, 0.f), 800.f);
  y2 = fminf(fmaxf(y2, 0.f), 608.f); x2 = fminf(fmaxf(x2, 0.f), 800.f);
  *(float4*)&roi[(size_t)n * 4] = make_float4(y1, x1, y2, x2);
  bool valid = ((y2 - y1) >= 16.f) && ((x2 - x1) >= 16.f);
  float sc = valid ? fg : -__builtin_huge_valf();
  unsigned m = __float_as_uint(sc);
  m = (m & 0x80000000u) ? ~m : (m | 0x80000000u);   // monotone map: larger score -> larger m
  unsigned km = ~m;                                  // ascending key = descending score
  keys[n] = ((u64)km << 32) | (unsigned)n;           // tie-break: lower index first
}

// -------------- LDS bitonic sort of one 2048 chunk (asc), 16 blocks ------------
// Replaces 4x8192 bitonic (91 phases on 4 CUs, ~95us est) with 16x2048
// (66 phases on 16 CUs). Keys unique -> any correct merge tree reproduces the
// exact same global top-6016 downstream.
__global__ __launch_bounds__(256) void sortchunk_kernel(u64* __restrict__ keys) {
  __shared__ u64 s[2048];
  const int tid = threadIdx.x;
  u64* base = keys + (size_t)blockIdx.x * 2048;
  for (int i = tid; i < 2048; i += 256) s[i] = base[i];
  __syncthreads();
  for (int k = 2; k <= 2048; k <<= 1) {
    for (int j = k >> 1; j > 0; j >>= 1) {
      for (int i = tid; i < 2048; i += 256) {
        int l = i ^ j;
        if (l > i) {
          u64 xa = s[i], xb = s[l];
          bool up = ((i & k) == 0);
          if ((xa > xb) == up) { s[i] = xb; s[l] = xa; }
        }
      }
      __syncthreads();
    }
  }
  for (int i = tid; i < 2048; i += 256) base[i] = s[i];
}

// ------------------------------ merge-path helper ------------------------------
__device__ inline void merge_path(const u64* __restrict__ A, int nA, const u64* __restrict__ B, int nB,
                                  u64* __restrict__ dst, int d0, int cnt, int outLimit) {
  if (d0 >= outLimit || d0 >= nA + nB) return;
  int lo = d0 > nB ? d0 - nB : 0;
  int hi = d0 < nA ? d0 : nA;
  while (lo < hi) {
    int mid = (lo + hi) >> 1;
    if (A[mid] <= B[d0 - 1 - mid]) lo = mid + 1; else hi = mid;
  }
  int i = lo, j = d0 - lo;
  int end = d0 + cnt;
  if (end > nA + nB) end = nA + nB;
  if (end > outLimit) end = outLimit;
  for (int q = d0; q < end; ++q) {
    u64 v;
    if (i < nA && (j >= nB || A[i] <= B[j])) v = A[i++]; else v = B[j++];
    dst[q] = v;
  }
}

// ------- 4-way merge (2 levels in LDS), truncated to first 6016, 4 blocks ------
// block b: chunks 4b..4b+3 (each 2048 asc) -> tmp[b*TOPN .. +6016)
__global__ __launch_bounds__(256) void merge4_kernel(const u64* __restrict__ keys, u64* __restrict__ tmp) {
  __shared__ u64 M01[4096];
  __shared__ u64 M23[4096];
  const int tid = threadIdx.x;
  const u64* c = keys + (size_t)blockIdx.x * 8192;
  merge_path(c,        2048, c + 2048, 2048, M01, tid * 16, 16, 4096);
  merge_path(c + 4096, 2048, c + 6144, 2048, M23, tid * 16, 16, 4096);
  __syncthreads();
  merge_path(M01, 4096, M23, 4096, tmp + (size_t)blockIdx.x * TOPN, tid * 24, 24, TOPN);
}

// ------ final: 4 lists of 6016 -> topk[6016] (2 levels in LDS), 1 block --------
__global__ __launch_bounds__(256) void mergefinal_kernel(const u64* __restrict__ tmp, u64* __restrict__ topk) {
  __shared__ u64 L0[TOPN];
  __shared__ u64 L1[TOPN];
  const int tid = threadIdx.x;
  merge_path(tmp,            TOPN, tmp + TOPN,     TOPN, L0, tid * 24, 24, TOPN);
  merge_path(tmp + 2 * TOPN, TOPN, tmp + 3 * TOPN, TOPN, L1, tid * 24, 24, TOPN);
  __syncthreads();
  merge_path(L0, TOPN, L1, TOPN, topk, tid * 24, 24, TOPN);
}

// ---------------- gather top-6000 boxes + areas + validity bitmask --------------
__global__ __launch_bounds__(256) void gather_kernel(const u64* __restrict__ topk, const float* __restrict__ roi,
                                                     float* __restrict__ tb, float* __restrict__ areaArr,
                                                     u64* __restrict__ valw) {
  int j = blockIdx.x * 256 + threadIdx.x;            // 6144 threads
  u64 key = (j < TOPN) ? topk[j] : ~0ull;
  bool valid = (j < PRE) && ((unsigned)(key >> 32) < 0xFF800000u);   // score > -inf
  if (j < PRE) {
    unsigned idx = (unsigned)key;
    float4 b = *(const float4*)&roi[(size_t)idx * 4];
    *(float4*)&tb[(size_t)j * 4] = b;
    areaArr[j] = (b.z - b.x) * (b.w - b.y);
  }
  u64 mask = __ballot(valid);
  if ((threadIdx.x & 63) == 0) {
    int wi = j >> 6;
    if (wi < NW) valw[wi] = mask;
  }
}

// --------------- suppression bit-matrix MT[w][i]: bits j in word w -------------
__global__ __launch_bounds__(256) void mask_kernel(const float* __restrict__ tb, const float* __restrict__ areaArr,
                                                   u64* __restrict__ MT) {
  int linear = blockIdx.x * 256 + threadIdx.x;
  if (linear >= NW * PRE) return;
  int w = linear / PRE;
  int i = linear - w * PRE;
  u64 bits = 0;
  int jbase = w * 64;
  if (jbase + 63 > i) {
    float4 bi = *(const float4*)&tb[(size_t)i * 4];
    float ai = areaArr[i];
    int jend = jbase + 64; if (jend > PRE) jend = PRE;
    int jst = jbase > i + 1 ? jbase : i + 1;
    for (int j = jst; j < jend; ++j) {
      float4 bj = *(const float4*)&tb[(size_t)j * 4];
      float ty1 = fmaxf(bi.x, bj.x);
      float tx1 = fmaxf(bi.y, bj.y);
      float ty2 = fminf(bi.z, bj.z);
      float tx2 = fminf(bi.w, bj.w);
      float ih = ty2 - ty1; if (ih < 0.f) ih = 0.f;
      float iw = tx2 - tx1; if (iw < 0.f) iw = 0.f;
      float inter = ih * iw;
      float denom = ai + areaArr[j] - inter;
      if (denom < 1e-9f) denom = 1e-9f;
      if (inter / denom > 0.7f) bits |= (1ull << (j - jbase));
    }
  }
  MT[(size_t)w * MTS + i] = bits;
}

__device__ inline u64 shfl_u64(u64 v, int src) {
  int lo = __shfl((int)(unsigned)(v & 0xffffffffull), src, 64);
  int hi = __shfl((int)(unsigned)(v >> 32), src, 64);
  return ((u64)(unsigned)hi << 32) | (unsigned)lo;
}

// ------------- single-wave greedy NMS scan + write first 300 kept --------------
__global__ __launch_bounds__(64) void nms_scan_kernel(const u64* __restrict__ MT, const u64* __restrict__ valw,
                                                      const float* __restrict__ tb, float* __restrict__ out) {
  __shared__ u64 removed[NW];
  __shared__ int keepids[POST];
  const int lane = threadIdx.x;
  for (int wk = lane; wk < NW; wk += 64) removed[wk] = 0;
  __syncthreads();
  int kept = 0;
  bool done = false;
  for (int g = 0; g < NW && !done; ++g) {
    int row = g * 64 + lane;
    u64 cur = (row < PRE) ? MT[(size_t)g * MTS + row] : 0ull;   // box row's own-word suppression bits
    u64 v = valw[g];
    u64 r = removed[g];
    u64 kb = 0;
    u64 remaining = v & ~r;
    while (remaining) {                                // uniform across lanes
      int c = __builtin_ctzll(remaining);
      if (lane == 0) keepids[kept] = g * 64 + c;
      kb |= (1ull << c);
      ++kept;
      if (kept >= POST) { done = true; break; }
      u64 cw = shfl_u64(cur, c);                       // broadcast lane c's word
      r |= cw;
      u64 above = (c == 63) ? 0ull : (~0ull << (c + 1));
      remaining = v & ~r & above;
    }
    if (!done) {
      __syncthreads();
      for (int wk = g + 1 + lane; wk < NW; wk += 64) {
        u64 acc2 = removed[wk];
        u64 m = kb;
        while (m) {
          int b = __builtin_ctzll(m); m &= m - 1;
          acc2 |= MT[(size_t)wk * MTS + g * 64 + b];
        }
        removed[wk] = acc2;
      }
      __syncthreads();
    }
  }
  __syncthreads();
  int kmax = kept < POST ? kept : POST;
  for (int rr = lane; rr < kmax; rr += 64) {
    float4 b = *(const float4*)&tb[(size_t)keepids[rr] * 4];
    *(float4*)&out[(size_t)rr * 4] = b;
  }
}

extern "C" void kernel_launch(void* const* d_in, const int* in_sizes, int n_in,
                              void* d_out, int out_size, void* d_ws, size_t ws_size,
                              hipStream_t stream) {
  (void)in_sizes; (void)n_in; (void)ws_size;
  const float* x  = (const float*)d_in[0];
  const float* w1 = (const float*)d_in[1];
  const float* b1 = (const float*)d_in[2];
  const float* lw = (const float*)d_in[3];
  const float* lb = (const float*)d_in[4];
  const float* sw = (const float*)d_in[5];
  const float* sb = (const float*)d_in[6];
  float* out = (float*)d_out;

  char* wp = (char*)d_ws;
  auto alloc = [&](size_t b) -> void* { void* p = wp; wp += (b + 255) & ~(size_t)255; return p; };
  float* xp      = (float*)alloc((size_t)CIN * PH * PW * 4);   // 4.26 MB
  float* wt      = (float*)alloc((size_t)4608 * CIN * 4);      // 9.44 MB
  float* part    = (float*)alloc((size_t)3 * CIN * HW * 4);    // 11.7 MB
  float* h1      = (float*)alloc((size_t)CIN * HW * 4);        // 3.89 MB
  float* wt2     = (float*)alloc((size_t)CIN * 64 * 4);
  float* c2      = (float*)alloc((size_t)64 * HW * 4);
  float* roi     = (float*)alloc((size_t)NA * 4 * 4);
  u64*   keys    = (u64*)alloc((size_t)NSORT * 8);
  u64*   tmp     = (u64*)alloc((size_t)NSORT * 8);
  u64*   topk    = (u64*)alloc((size_t)8192 * 8);
  float* tb      = (float*)alloc((size_t)PRE * 4 * 4);
  float* areaArr = (float*)alloc((size_t)PRE * 4);
  u64*   valw    = (u64*)alloc((size_t)NW * 8);
  u64*   MT      = (u64*)alloc((size_t)NW * MTS * 8);          // 4.52 MB

  hipMemsetAsync(d_out, 0, (size_t)out_size * 4, stream);

  pad_kernel<<<(CIN * PH * PW) / 256, 256, 0, stream>>>(x, xp);
  wtrans_kernel<<<dim3(32, 32), 256, 0, stream>>>(w1, wt);
  wt2prep_kernel<<<(CIN * 64) / 256, 256, 0, stream>>>(lw, sw, wt2);
  conv_gemm_kernel<<<dim3(8, 30, 3), 256, 0, stream>>>(wt, xp, part);
  reduce_relu_kernel<<<(CIN * HW) / 256, 256, 0, stream>>>(part, b1, h1);
  heads_gemm_kernel<<<30, 256, 0, stream>>>(wt2, h1, lb, sb, c2);
  decode_kernel<<<NSORT / 256, 256, 0, stream>>>(c2, roi, keys);
  sortchunk_kernel<<<16, 256, 0, stream>>>(keys);
  merge4_kernel<<<4, 256, 0, stream>>>(keys, tmp);
  mergefinal_kernel<<<1, 256, 0, stream>>>(tmp, topk);
  gather_kernel<<<24, 256, 0, stream>>>(topk, roi, tb, areaArr, valw);
  mask_kernel<<<(NW * PRE + 255) / 256, 256, 0, stream>>>(tb, areaArr, MT);
  nms_scan_kernel<<<1, 64, 0, stream>>>(MT, valw, tb, out);
}

// Round 6
// 456.010 us; speedup vs baseline: 1.6932x; 1.1573x over previous
//
#include <hip/hip_runtime.h>
#include <cstdint>
#include <cstddef>

typedef unsigned long long u64;

#define CIN   512
#define H     38
#define W     50
#define HW    1900
#define PH    40
#define PW    52
#define NA    17100
#define NSORT 32768
#define PRE   6000
#define POST  300
#define NW    94        // ceil(6000/64)
#define MTS   6016      // MT row stride (padded)
#define TOPN  6016      // padded top-k (>= PRE, x64 aligned)

// ANCHOR_BASE, fp32-exact decimal literals
__constant__ float c_AB[36] = {
  -37.254833f,  -82.50967f,   53.254833f,  98.50967f,
  -82.50967f,  -173.01933f,   98.50967f,  189.01933f,
 -173.01933f,  -354.03867f,  189.01933f,  370.03867f,
  -56.f, -56.f, 72.f, 72.f,
 -120.f,-120.f,136.f,136.f,
 -248.f,-248.f,264.f,264.f,
  -82.50967f,  -37.254833f,   98.50967f,  53.254833f,
 -173.01933f,  -82.50967f,   189.01933f,  98.50967f,
 -354.03867f, -173.01933f,   370.03867f, 189.01933f
};

// ------- fused prep: pad (4160 blks) + wtrans (1024 blks) + wt2prep (128) -------
// pad:    x(512,38,50) -> xp(512,40,52)
// wtrans: w1(o,i,ky,kx) -> wt[k=r*512+i][o]
// wt2:    loc_w/score_w -> wt2[k][o(64)] and transposed wt2t[o][k] for heads
__global__ __launch_bounds__(256) void prep_kernel(const float* __restrict__ x, float* __restrict__ xp,
                                                   const float* __restrict__ w1, float* __restrict__ wt,
                                                   const float* __restrict__ lw, const float* __restrict__ sw,
                                                   float* __restrict__ wt2, float* __restrict__ wt2t) {
  __shared__ float tile[9][16][17];
  int b = blockIdx.x;
  if (b < 4160) {                                    // ---- pad ----
    int idx = b * 256 + threadIdx.x;                 // exactly 512*40*52
    int c   = idx / (PH * PW);
    int rem = idx - c * (PH * PW);
    int yy  = rem / PW;
    int xx  = rem - yy * PW;
    float v = 0.f;
    if (yy >= 1 && yy <= H && xx >= 1 && xx <= W)
      v = x[(size_t)c * HW + (yy - 1) * W + (xx - 1)];
    xp[idx] = v;
  } else if (b < 5184) {                             // ---- wtrans ----
    int t2 = b - 4160;
    int o0 = (t2 & 31) * 16, i0 = (t2 >> 5) * 16;
    int tx = threadIdx.x & 15, ty = threadIdx.x >> 4;
    #pragma unroll
    for (int r = 0; r < 9; ++r)
      tile[r][tx][ty] = w1[((size_t)(o0 + ty) * CIN + (i0 + tx)) * 9 + r];
    __syncthreads();
    #pragma unroll
    for (int r = 0; r < 9; ++r)
      wt[((size_t)r * CIN + i0 + ty) * CIN + o0 + tx] = tile[r][ty][tx];
  } else {                                           // ---- wt2prep (+ transpose) ----
    int t = (b - 5184) * 256 + threadIdx.x;          // < 512*64
    int k = t >> 6, o = t & 63;
    float v = 0.f;
    if (o < 36)      v = lw[o * CIN + k];
    else if (o < 54) v = sw[(o - 36) * CIN + k];
    wt2[t] = v;
    wt2t[(size_t)o * CIN + k] = v;
  }
}

// --------- conv1 as implicit GEMM, fp32, deterministic 3-way K-split ----------
// r0 configuration VERBATIM: 64x64 tile, 4x4 micro, 720 blocks (2.8 waves/SIMD).
// Counter-validated LDS-pipe wall: ds_read_b128 instrs x 12cyc / 256 CU = 171us
// = measured. Rounds 1-4 proved restructures lose. Bit-exact k-order.
__global__ __launch_bounds__(256) void conv_gemm_kernel(const float* __restrict__ wt, const float* __restrict__ xp,
                                                        float* __restrict__ part) {
  __shared__ __align__(16) float As[16][64];
  __shared__ __align__(16) float Bs[16][64];
  const int tid   = threadIdx.x;
  const int obase = blockIdx.x * 64;
  const int pbase = blockIdx.y * 64;
  const int split = blockIdx.z;
  const int kbeg = split * 1536, kend = kbeg + 1536;
  const int krow = tid >> 4;          // staging row 0..15
  const int c4   = (tid & 15) * 4;    // staging col
  const int to   = (tid & 15) * 4;    // output o quad
  const int tp   = (tid >> 4) * 4;    // output p quad
  float acc[4][4] = {};
  float av[4], bv[4];

  auto loadAB = [&](int k0) {
    int k = k0 + krow;
    const float* ap = &wt[(size_t)k * CIN + obase + c4];
    av[0] = ap[0]; av[1] = ap[1]; av[2] = ap[2]; av[3] = ap[3];
    int r = k >> 9;            // k = r*512 + i
    int i = k & 511;
    int ky = r / 3, kx = r - ky * 3;
    const float* xpi = &xp[(size_t)i * (PH * PW)];
    #pragma unroll
    for (int j = 0; j < 4; ++j) {
      int p = pbase + c4 + j;
      float v = 0.f;
      if (p < HW) {
        int y = p / W, xx = p - y * W;
        v = xpi[(y + ky) * PW + xx + kx];
      }
      bv[j] = v;
    }
  };

  loadAB(kbeg);
  for (int k0 = kbeg; k0 < kend; k0 += 16) {
    __syncthreads();
    *(float4*)&As[krow][c4] = make_float4(av[0], av[1], av[2], av[3]);
    *(float4*)&Bs[krow][c4] = make_float4(bv[0], bv[1], bv[2], bv[3]);
    __syncthreads();
    if (k0 + 16 < kend) loadAB(k0 + 16);
    #pragma unroll
    for (int kk = 0; kk < 16; ++kk) {
      float4 a4 = *(const float4*)&As[kk][to];
      float4 b4 = *(const float4*)&Bs[kk][tp];
      float ar[4] = {a4.x, a4.y, a4.z, a4.w};
      float br[4] = {b4.x, b4.y, b4.z, b4.w};
      #pragma unroll
      for (int ii = 0; ii < 4; ++ii)
        #pragma unroll
        for (int jj = 0; jj < 4; ++jj)
          acc[ii][jj] += ar[ii] * br[jj];
    }
  }
  float* dst = part + (size_t)split * CIN * HW;
  #pragma unroll
  for (int ii = 0; ii < 4; ++ii) {
    int o = obase + to + ii;
    int p = pbase + tp;
    float* rowp = dst + (size_t)o * HW;
    if (p + 3 < HW) {
      *(float4*)&rowp[p] = make_float4(acc[ii][0], acc[ii][1], acc[ii][2], acc[ii][3]);
    } else {
      #pragma unroll
      for (int jj = 0; jj < 4; ++jj) if (p + jj < HW) rowp[p + jj] = acc[ii][jj];
    }
  }
}

// ------------------- h1 = relu(part0+part1+part2 + bias) ----------------------
__global__ __launch_bounds__(256) void reduce_relu_kernel(const float* __restrict__ part, const float* __restrict__ b1,
                                                          float* __restrict__ h1) {
  int idx = blockIdx.x * 256 + threadIdx.x;          // exactly 512*1900
  int o = idx / HW;
  float v = part[idx] + part[(size_t)CIN * HW + idx] + part[(size_t)2 * CIN * HW + idx] + b1[o];
  h1[idx] = v > 0.f ? v : 0.f;
}

// ----------- heads as per-wave dot products: c2[o][p], o<54 ------------------
// Old heads: 30 blocks = 30 CUs, 1 wave/SIMD, latency-naked (r4 failure mode).
// New: 1 wave per (o, 64-p group); A = wt2t row (wave-uniform -> scalarized),
// B = coalesced 256B loads; k unrolled x16. 1620 blocks ~ 1.6 waves/SIMD over
// all CUs. Bit-exact: ascending k, one fma per k, single accumulator (same
// order as old 4x4 kernel's acc).
__global__ __launch_bounds__(64) void heads_dot_kernel(const float* __restrict__ wt2t, const float* __restrict__ h1,
                                                       const float* __restrict__ lb, const float* __restrict__ sb,
                                                       float* __restrict__ c2) {
  const int o = blockIdx.x;                          // 0..53
  const int p = blockIdx.y * 64 + threadIdx.x;
  const bool pv = (p < HW);
  const float* __restrict__ ap = wt2t + ((size_t)o << 9);
  const float* __restrict__ bp = h1 + (pv ? p : 0);
  float acc = 0.f;
  #pragma unroll 1
  for (int g = 0; g < CIN; g += 16) {
    float4 a0 = *(const float4*)(ap + g);
    float4 a1 = *(const float4*)(ap + g + 4);
    float4 a2 = *(const float4*)(ap + g + 8);
    float4 a3 = *(const float4*)(ap + g + 12);
    float bb[16];
    #pragma unroll
    for (int u = 0; u < 16; ++u) bb[u] = bp[(size_t)(g + u) * HW];
    acc += a0.x * bb[0];  acc += a0.y * bb[1];  acc += a0.z * bb[2];  acc += a0.w * bb[3];
    acc += a1.x * bb[4];  acc += a1.y * bb[5];  acc += a1.z * bb[6];  acc += a1.w * bb[7];
    acc += a2.x * bb[8];  acc += a2.y * bb[9];  acc += a2.z * bb[10]; acc += a2.w * bb[11];
    acc += a3.x * bb[12]; acc += a3.y * bb[13]; acc += a3.z * bb[14]; acc += a3.w * bb[15];
  }
  if (pv) {
    float bias = (o < 36) ? lb[o] : sb[o - 36];
    c2[(size_t)o * HW + p] = acc + bias;
  }
}

// ---------------- decode anchors -> roi, validity, sortable key ----------------
__global__ __launch_bounds__(256) void decode_kernel(const float* __restrict__ c2, float* __restrict__ roi,
                                                     u64* __restrict__ keys) {
  int n = blockIdx.x * 256 + threadIdx.x;
  if (n >= NSORT) return;
  if (n >= NA) { keys[n] = ~0ull; return; }
  unsigned p = (unsigned)n / 9u;
  unsigned a = (unsigned)n - p * 9u;
  unsigned y = p / 50u;
  unsigned x = p - y * 50u;
  float dy = c2[(a * 4 + 0) * HW + p];
  float dx = c2[(a * 4 + 1) * HW + p];
  float dh = c2[(a * 4 + 2) * HW + p];
  float dw = c2[(a * 4 + 3) * HW + p];
  float fg = c2[(37 + a * 2) * HW + p];           // score channel a*2+1, rows offset 36
  float sy = (float)(y * 16u), sx = (float)(x * 16u);
  float ay1 = sy + c_AB[a * 4 + 0], ax1 = sx + c_AB[a * 4 + 1];
  float ay2 = sy + c_AB[a * 4 + 2], ax2 = sx + c_AB[a * 4 + 3];
  float ahh = ay2 - ay1, aww = ax2 - ax1;
  float acy = ay1 + 0.5f * ahh, acx = ax1 + 0.5f * aww;
  float cy = dy * ahh + acy, cx = dx * aww + acx;
  float hh = expf(dh) * ahh, ww = expf(dw) * aww;
  float y1 = cy - 0.5f * hh, x1 = cx - 0.5f * ww;
  float y2 = cy + 0.5f * hh, x2 = cx + 0.5f * ww;
  y1 = fminf(fmaxf(y1, 0.f), 608.f); x1 = fminf(fmaxf(x1, 0.f), 800.f);
  y2 = fminf(fmaxf(y2, 0.f), 608.f); x2 = fminf(fmaxf(x2, 0.f), 800.f);
  *(float4*)&roi[(size_t)n * 4] = make_float4(y1, x1, y2, x2);
  bool valid = ((y2 - y1) >= 16.f) && ((x2 - x1) >= 16.f);
  float sc = valid ? fg : -__builtin_huge_valf();
  unsigned m = __float_as_uint(sc);
  m = (m & 0x80000000u) ? ~m : (m | 0x80000000u);   // monotone map: larger score -> larger m
  unsigned km = ~m;                                  // ascending key = descending score
  keys[n] = ((u64)km << 32) | (unsigned)n;           // tie-break: lower index first
}

// -------------- LDS bitonic sort of one 2048 chunk (asc), 16 blocks ------------
__global__ __launch_bounds__(256) void sortchunk_kernel(u64* __restrict__ keys) {
  __shared__ u64 s[2048];
  const int tid = threadIdx.x;
  u64* base = keys + (size_t)blockIdx.x * 2048;
  for (int i = tid; i < 2048; i += 256) s[i] = base[i];
  __syncthreads();
  for (int k = 2; k <= 2048; k <<= 1) {
    for (int j = k >> 1; j > 0; j >>= 1) {
      for (int i = tid; i < 2048; i += 256) {
        int l = i ^ j;
        if (l > i) {
          u64 xa = s[i], xb = s[l];
          bool up = ((i & k) == 0);
          if ((xa > xb) == up) { s[i] = xb; s[l] = xa; }
        }
      }
      __syncthreads();
    }
  }
  for (int i = tid; i < 2048; i += 256) base[i] = s[i];
}

// ------------------------------ merge-path helper ------------------------------
__device__ inline void merge_path(const u64* __restrict__ A, int nA, const u64* __restrict__ B, int nB,
                                  u64* __restrict__ dst, int d0, int cnt, int outLimit) {
  if (d0 >= outLimit || d0 >= nA + nB) return;
  int lo = d0 > nB ? d0 - nB : 0;
  int hi = d0 < nA ? d0 : nA;
  while (lo < hi) {
    int mid = (lo + hi) >> 1;
    if (A[mid] <= B[d0 - 1 - mid]) lo = mid + 1; else hi = mid;
  }
  int i = lo, j = d0 - lo;
  int end = d0 + cnt;
  if (end > nA + nB) end = nA + nB;
  if (end > outLimit) end = outLimit;
  for (int q = d0; q < end; ++q) {
    u64 v;
    if (i < nA && (j >= nB || A[i] <= B[j])) v = A[i++]; else v = B[j++];
    dst[q] = v;
  }
}

// ------- 4-way merge (2 levels in LDS), truncated to first 6016, 4 blocks ------
__global__ __launch_bounds__(256) void merge4_kernel(const u64* __restrict__ keys, u64* __restrict__ tmp) {
  __shared__ u64 M01[4096];
  __shared__ u64 M23[4096];
  const int tid = threadIdx.x;
  const u64* c = keys + (size_t)blockIdx.x * 8192;
  merge_path(c,        2048, c + 2048, 2048, M01, tid * 16, 16, 4096);
  merge_path(c + 4096, 2048, c + 6144, 2048, M23, tid * 16, 16, 4096);
  __syncthreads();
  merge_path(M01, 4096, M23, 4096, tmp + (size_t)blockIdx.x * TOPN, tid * 24, 24, TOPN);
}

// --- final: 4 lists of 6016 -> top-6016 (LDS) + fused gather (tb/area/valw) ----
// 144KB static LDS (<=160KB/CU; r5 already ran 96KB). Drops the topk global
// round-trip and the separate gather launch. Same merges, same gather math.
__global__ __launch_bounds__(256) void mergefinal_gather_kernel(const u64* __restrict__ tmp,
                                                                const float* __restrict__ roi,
                                                                float* __restrict__ tb, float* __restrict__ areaArr,
                                                                u64* __restrict__ valw) {
  __shared__ u64 L0[TOPN];
  __shared__ u64 L1[TOPN];
  __shared__ u64 F[TOPN];
  const int tid = threadIdx.x;
  merge_path(tmp,            TOPN, tmp + TOPN,     TOPN, L0, tid * 24, 24, TOPN);
  merge_path(tmp + 2 * TOPN, TOPN, tmp + 3 * TOPN, TOPN, L1, tid * 24, 24, TOPN);
  __syncthreads();
  merge_path(L0, TOPN, L1, TOPN, F, tid * 24, 24, TOPN);
  __syncthreads();
  for (int j0 = 0; j0 < TOPN; j0 += 256) {
    int j = j0 + tid;
    u64 key = F[j];
    bool valid = (j < PRE) && ((unsigned)(key >> 32) < 0xFF800000u);   // score > -inf
    if (j < PRE) {
      unsigned idx = (unsigned)key;
      float4 bx = *(const float4*)&roi[(size_t)idx * 4];
      *(float4*)&tb[(size_t)j * 4] = bx;
      areaArr[j] = (bx.z - bx.x) * (bx.w - bx.y);
    }
    u64 mask = __ballot(valid);
    if ((tid & 63) == 0) {
      int wi = j >> 6;
      if (wi < NW) valw[wi] = mask;
    }
  }
}

// --------------- suppression bit-matrix MT[w][i]: bits j in word w -------------
__global__ __launch_bounds__(256) void mask_kernel(const float* __restrict__ tb, const float* __restrict__ areaArr,
                                                   u64* __restrict__ MT) {
  int linear = blockIdx.x * 256 + threadIdx.x;
  if (linear >= NW * PRE) return;
  int w = linear / PRE;
  int i = linear - w * PRE;
  u64 bits = 0;
  int jbase = w * 64;
  if (jbase + 63 > i) {
    float4 bi = *(const float4*)&tb[(size_t)i * 4];
    float ai = areaArr[i];
    int jend = jbase + 64; if (jend > PRE) jend = PRE;
    int jst = jbase > i + 1 ? jbase : i + 1;
    for (int j = jst; j < jend; ++j) {
      float4 bj = *(const float4*)&tb[(size_t)j * 4];
      float ty1 = fmaxf(bi.x, bj.x);
      float tx1 = fmaxf(bi.y, bj.y);
      float ty2 = fminf(bi.z, bj.z);
      float tx2 = fminf(bi.w, bj.w);
      float ih = ty2 - ty1; if (ih < 0.f) ih = 0.f;
      float iw = tx2 - tx1; if (iw < 0.f) iw = 0.f;
      float inter = ih * iw;
      float denom = ai + areaArr[j] - inter;
      if (denom < 1e-9f) denom = 1e-9f;
      if (inter / denom > 0.7f) bits |= (1ull << (j - jbase));
    }
  }
  MT[(size_t)w * MTS + i] = bits;
}

__device__ inline u64 shfl_u64(u64 v, int src) {
  int lo = __shfl((int)(unsigned)(v & 0xffffffffull), src, 64);
  int hi = __shfl((int)(unsigned)(v >> 32), src, 64);
  return ((u64)(unsigned)hi << 32) | (unsigned)lo;
}
__device__ inline u64 shfl_u64_xor(u64 v, int m) {
  int lo = __shfl_xor((int)(unsigned)(v & 0xffffffffull), m, 64);
  int hi = __shfl_xor((int)(unsigned)(v >> 32), m, 64);
  return ((u64)(unsigned)hi << 32) | (unsigned)lo;
}

// --------- single-wave greedy NMS, demand-pull rem (no removed[] array) --------
// Old version: per kept-box bit, one gathered load in a serial dependent while
// over ALL future words -> ~450 x ~500-900cyc = 100-200us on one wave.
// New: at group g, rem = OR over kept c of MT[g][c]: <=5 INDEPENDENT parallel
// 64-lane gathered loads + 6-step shfl OR-reduce (~1.3k cyc/group). rem at
// group entry == old removed[g] (kept list at that point = kept in groups < g);
// within-group suppression via cur-shfl unchanged -> identical keep decisions.
__global__ __launch_bounds__(64) void nms_scan_kernel(const u64* __restrict__ MT, const u64* __restrict__ valw,
                                                      const float* __restrict__ tb, float* __restrict__ out) {
  __shared__ int keepids[POST];
  const int lane = threadIdx.x;
  int kept = 0;
  bool done = false;
  for (int g = 0; g < NW && !done; ++g) {
    const u64* __restrict__ rowg = MT + (size_t)g * MTS;
    u64 rem = 0;
    for (int base = 0; base < kept; base += 64) {
      int kidx = base + lane;
      u64 v = (kidx < kept) ? rowg[keepids[kidx]] : 0ull;
      rem |= v;
    }
    #pragma unroll
    for (int s = 32; s > 0; s >>= 1) rem |= shfl_u64_xor(rem, s);
    int row = g * 64 + lane;
    u64 cur = (row < PRE) ? rowg[row] : 0ull;        // own-word suppression bits
    u64 remaining = valw[g] & ~rem;
    while (remaining) {                               // uniform across lanes
      int c = __builtin_ctzll(remaining);
      if (lane == 0) keepids[kept] = g * 64 + c;
      ++kept;
      if (kept >= POST) { done = true; break; }
      u64 cw = shfl_u64(cur, c);                      // broadcast lane c's word
      u64 above = (c == 63) ? 0ull : (~0ull << (c + 1));
      remaining = remaining & ~cw & above;
    }
  }
  __syncthreads();
  int kmax = kept < POST ? kept : POST;
  for (int rr = lane; rr < kmax; rr += 64) {
    float4 b = *(const float4*)&tb[(size_t)keepids[rr] * 4];
    *(float4*)&out[(size_t)rr * 4] = b;
  }
}

extern "C" void kernel_launch(void* const* d_in, const int* in_sizes, int n_in,
                              void* d_out, int out_size, void* d_ws, size_t ws_size,
                              hipStream_t stream) {
  (void)in_sizes; (void)n_in; (void)ws_size;
  const float* x  = (const float*)d_in[0];
  const float* w1 = (const float*)d_in[1];
  const float* b1 = (const float*)d_in[2];
  const float* lw = (const float*)d_in[3];
  const float* lb = (const float*)d_in[4];
  const float* sw = (const float*)d_in[5];
  const float* sb = (const float*)d_in[6];
  float* out = (float*)d_out;

  char* wp = (char*)d_ws;
  auto alloc = [&](size_t b) -> void* { void* p = wp; wp += (b + 255) & ~(size_t)255; return p; };
  float* xp      = (float*)alloc((size_t)CIN * PH * PW * 4);   // 4.26 MB
  float* wt      = (float*)alloc((size_t)4608 * CIN * 4);      // 9.44 MB
  float* part    = (float*)alloc((size_t)3 * CIN * HW * 4);    // 11.7 MB
  float* h1      = (float*)alloc((size_t)CIN * HW * 4);        // 3.89 MB
  float* wt2     = (float*)alloc((size_t)CIN * 64 * 4);
  float* wt2t    = (float*)alloc((size_t)64 * CIN * 4);
  float* c2      = (float*)alloc((size_t)64 * HW * 4);
  float* roi     = (float*)alloc((size_t)NA * 4 * 4);
  u64*   keys    = (u64*)alloc((size_t)NSORT * 8);
  u64*   tmp     = (u64*)alloc((size_t)NSORT * 8);
  float* tb      = (float*)alloc((size_t)PRE * 4 * 4);
  float* areaArr = (float*)alloc((size_t)PRE * 4);
  u64*   valw    = (u64*)alloc((size_t)NW * 8);
  u64*   MT      = (u64*)alloc((size_t)NW * MTS * 8);          // 4.52 MB

  hipMemsetAsync(d_out, 0, (size_t)out_size * 4, stream);

  prep_kernel<<<5312, 256, 0, stream>>>(x, xp, w1, wt, lw, sw, wt2, wt2t);
  conv_gemm_kernel<<<dim3(8, 30, 3), 256, 0, stream>>>(wt, xp, part);
  reduce_relu_kernel<<<(CIN * HW) / 256, 256, 0, stream>>>(part, b1, h1);
  heads_dot_kernel<<<dim3(54, 30), 64, 0, stream>>>(wt2t, h1, lb, sb, c2);
  decode_kernel<<<NSORT / 256, 256, 0, stream>>>(c2, roi, keys);
  sortchunk_kernel<<<16, 256, 0, stream>>>(keys);
  merge4_kernel<<<4, 256, 0, stream>>>(keys, tmp);
  mergefinal_gather_kernel<<<1, 256, 0, stream>>>(tmp, roi, tb, areaArr, valw);
  mask_kernel<<<(NW * PRE + 255) / 256, 256, 0, stream>>>(tb, areaArr, MT);
  nms_scan_kernel<<<1, 64, 0, stream>>>(MT, valw, tb, out);
}